// Round 5
// baseline (1395.727 us; speedup 1.0000x reference)
//
#include <hip/hip_runtime.h>

// Problem constants (from reference)
constexpr int N_PART = 100000;
constexpr int N_EDGE = 6400000;
constexpr float SUPPORT = 0.05f;
constexpr float PI_F = 3.14159265358979323846f;

// ===========================================================================
// R5 pivot: flat 2-pass pipeline with HW global atomics.
// Evidence (R1-R4): any per-edge divergent LDS op costs ~5 cyc/lane on the
// CU's single LDS pipe -> ~10 cyc/edge/CU floor per pass, occupancy-
// independent. The sorted 3-pass design pays that floor 3x plus 256 MB of
// record round-trips. Global HW atomics (global_atomic_add_f32, fire-and-
// forget) execute at the cache side across 8 XCDs — off the CU pipes.
// normals/out are 800 KB (L2-resident), neighbors uniform -> no hotspots.
//   pass1: per edge, 1 L2 gather (fac[j].x) + 2 atomics into normals[i]
//   pass2: per edge, 3 L2 gathers (fac.y, n_j, n_i) + 2 atomics into out[i]
// All streaming reads coalesced int4/float4, 8 edges/thread for MLP.
// ===========================================================================

// HW fp32 atomic (global_atomic_add_f32) — default atomicAdd(float*) can
// lower to a CAS loop; unsafeAtomicAdd guarantees the HW instruction.
__device__ __forceinline__ void gAdd(float* p, float v) {
#if defined(__HIP_PLATFORM_AMD__) || defined(__HIP_PLATFORM_HCC__)
    unsafeAtomicAdd(p, v);
#else
    atomicAdd(p, v);
#endif
}

// --- Prep: per-particle factors + zero both accumulators (one N-thread pass)
__global__ __launch_bounds__(256) void prep_zero(
    const float* __restrict__ areas,
    const float* __restrict__ dens,
    const float* __restrict__ rest,
    float2* __restrict__ fac,
    float2* __restrict__ normals,
    float2* __restrict__ out)
{
    int p = blockIdx.x * blockDim.x + threadIdx.x;
    if (p < N_PART) {
        fac[p]     = make_float2(areas[p] / dens[p], areas[p] * rest[p]);
        normals[p] = make_float2(0.0f, 0.0f);
        out[p]     = make_float2(0.0f, 0.0f);
    }
}

// --- Pass 1: normals[i] += SUPPORT * (areas[j]/dens[j]) * dWdq(q) * d
// Note SUPPORT * (1/SUPPORT) cancels: s = fac.x * C * (-20 q (1-q)^3).
// 8 edges/thread; all list reads coalesced 16 B.
__global__ __launch_bounds__(256) void flat_pass1(
    const int* __restrict__ nb,        // [2*E]
    const float2* __restrict__ fac,    // [N]
    const float* __restrict__ q,       // [E]
    const float* __restrict__ dist,    // [E,2]
    float* __restrict__ norm)          // [2*N] zeroed
{
    const int t = blockIdx.x * blockDim.x + threadIdx.x;   // 800000 threads
    const int e8 = t * 8;
    if (e8 >= N_EDGE) return;

    const int4*   nbi4 = (const int4*)nb;
    const int4*   nbj4 = (const int4*)(nb + N_EDGE);
    const float4* q4   = (const float4*)q;
    const float4* d4   = (const float4*)dist;

    int4   ia = nbi4[2 * t],     ib = nbi4[2 * t + 1];
    int4   ja = nbj4[2 * t],     jb = nbj4[2 * t + 1];
    float4 qa = q4[2 * t],       qb = q4[2 * t + 1];
    float4 dA = d4[4 * t], dB = d4[4 * t + 1], dC = d4[4 * t + 2], dD = d4[4 * t + 3];

    const float Cm20 = -20.0f * 7.0f / (PI_F * SUPPORT * SUPPORT);

    int   iv[8] = { ia.x, ia.y, ia.z, ia.w, ib.x, ib.y, ib.z, ib.w };
    int   jv[8] = { ja.x, ja.y, ja.z, ja.w, jb.x, jb.y, jb.z, jb.w };
    float qv[8] = { qa.x, qa.y, qa.z, qa.w, qb.x, qb.y, qb.z, qb.w };
    float dx[8] = { dA.x, dA.z, dB.x, dB.z, dC.x, dC.z, dD.x, dD.z };
    float dy[8] = { dA.y, dA.w, dB.y, dB.w, dC.y, dC.w, dD.y, dD.w };

    float fx[8];
    #pragma unroll
    for (int k = 0; k < 8; ++k)                 // issue all gathers first (MLP)
        fx[k] = fac[jv[k]].x;

    #pragma unroll
    for (int k = 0; k < 8; ++k) {
        float qq  = qv[k];
        float omq = fmaxf(1.0f - qq, 0.0f);
        float s   = fx[k] * Cm20 * qq * omq * omq * omq;
        gAdd(&norm[2 * iv[k]],     s * dx[k]);
        gAdd(&norm[2 * iv[k] + 1], s * dy[k]);
    }
}

// --- Pass 2: out[i] += (n_j - n_i) + areas[j]*rest[j]*kern(q)*d
__global__ __launch_bounds__(256) void flat_pass2(
    const int* __restrict__ nb,
    const float2* __restrict__ fac,
    const float* __restrict__ q,
    const float* __restrict__ dist,
    const float2* __restrict__ normals,  // [N] complete
    float* __restrict__ out)             // [2*N] zeroed
{
    const int t = blockIdx.x * blockDim.x + threadIdx.x;
    const int e8 = t * 8;
    if (e8 >= N_EDGE) return;

    const int4*   nbi4 = (const int4*)nb;
    const int4*   nbj4 = (const int4*)(nb + N_EDGE);
    const float4* q4   = (const float4*)q;
    const float4* d4   = (const float4*)dist;

    int4   ia = nbi4[2 * t],     ib = nbi4[2 * t + 1];
    int4   ja = nbj4[2 * t],     jb = nbj4[2 * t + 1];
    float4 qa = q4[2 * t],       qb = q4[2 * t + 1];
    float4 dA = d4[4 * t], dB = d4[4 * t + 1], dC = d4[4 * t + 2], dD = d4[4 * t + 3];

    int   iv[8] = { ia.x, ia.y, ia.z, ia.w, ib.x, ib.y, ib.z, ib.w };
    int   jv[8] = { ja.x, ja.y, ja.z, ja.w, jb.x, jb.y, jb.z, jb.w };
    float qv[8] = { qa.x, qa.y, qa.z, qa.w, qb.x, qb.y, qb.z, qb.w };
    float dx[8] = { dA.x, dA.z, dB.x, dB.z, dC.x, dC.z, dD.x, dD.z };
    float dy[8] = { dA.y, dA.w, dB.y, dB.w, dC.y, dC.w, dD.y, dD.w };

    float  fy[8];
    float2 nj[8], ni[8];
    #pragma unroll
    for (int k = 0; k < 8; ++k) {               // issue all gathers first (MLP)
        fy[k] = fac[jv[k]].y;
        nj[k] = normals[jv[k]];
        ni[k] = normals[iv[k]];
    }

    #pragma unroll
    for (int k = 0; k < 8; ++k) {
        float qq  = qv[k];
        float qm1 = qq - 1.0f;
        float tt  = qm1 * qm1 * qm1 * qq * qq * qq;
        float kern = (qq <= 0.5f) ? fmaf(128.0f, tt, 1.0f) : 64.0f * tt;
        float fc  = fy[k] * kern;
        gAdd(&out[2 * iv[k]],     nj[k].x - ni[k].x + fc * dx[k]);
        gAdd(&out[2 * iv[k] + 1], nj[k].y - ni[k].y + fc * dy[k]);
    }
}

// ===========================================================================
// Fallback: minimal-workspace atomic path (full compute inline).
// ===========================================================================
__global__ __launch_bounds__(256) void fb_zero2(float* __restrict__ a,
                                                float* __restrict__ b, int n) {
    int idx = blockIdx.x * blockDim.x + threadIdx.x;
    if (idx < n) { a[idx] = 0.0f; b[idx] = 0.0f; }
}

__global__ __launch_bounds__(256) void fb_pass1_atomic(
    const int* __restrict__ nb, const float* __restrict__ areas,
    const float* __restrict__ dens, const float* __restrict__ q,
    const float2* __restrict__ dist, float* __restrict__ normals)
{
    int e = blockIdx.x * blockDim.x + threadIdx.x;
    if (e >= N_EDGE) return;
    int i = nb[e];
    int j = nb[N_EDGE + e];
    float qq  = q[e];
    float fac = areas[j] / dens[j];
    const float Cw = 7.0f / (PI_F * SUPPORT * SUPPORT);
    float omq  = fmaxf(1.0f - qq, 0.0f);
    float dWdq = Cw * (-20.0f * qq * omq * omq * omq) * (1.0f / SUPPORT);
    float s = SUPPORT * fac * dWdq;
    float2 d = dist[e];
    atomicAdd(&normals[2 * i],     s * d.x);
    atomicAdd(&normals[2 * i + 1], s * d.y);
}

__global__ __launch_bounds__(256) void fb_pass2_atomic(
    const int* __restrict__ nb, const float* __restrict__ areas,
    const float* __restrict__ rest, const float* __restrict__ q,
    const float2* __restrict__ dist, const float2* __restrict__ normals,
    float* __restrict__ out)
{
    int e = blockIdx.x * blockDim.x + threadIdx.x;
    if (e >= N_EDGE) return;
    int i = nb[e];
    int j = nb[N_EDGE + e];
    float2 ni = normals[i];
    float2 nj = normals[j];
    float qq  = q[e];
    float fc  = areas[j] * rest[j];
    float qm1 = qq - 1.0f;
    float t   = qm1 * qm1 * qm1 * qq * qq * qq;
    float kern = (qq <= 0.5f) ? fmaf(128.0f, t, 1.0f) : 64.0f * t;
    float2 d = dist[e];
    atomicAdd(&out[2 * i],     -(ni.x - nj.x) + fc * kern * d.x);
    atomicAdd(&out[2 * i + 1], -(ni.y - nj.y) + fc * kern * d.y);
}

// ===========================================================================
extern "C" void kernel_launch(void* const* d_in, const int* in_sizes, int n_in,
                              void* d_out, int out_size, void* d_ws, size_t ws_size,
                              hipStream_t stream) {
    const int*   nb    = (const int*)d_in[0];     // [2*E]
    const float* areas = (const float*)d_in[1];   // [N]
    const float* dens  = (const float*)d_in[2];   // [N]
    const float* rest  = (const float*)d_in[3];   // [N]
    const float* q     = (const float*)d_in[4];   // [E]
    const float* dist  = (const float*)d_in[5];   // [E,2]
    float* out = (float*)d_out;                   // [N,2]

    // Workspace: fac[N] float2 + normals[N] float2
    size_t off = 0;
    auto take = [&](size_t bytes) { size_t o = off; off += (bytes + 255) & ~(size_t)255; return o; };
    size_t o_fac     = take((size_t)N_PART * sizeof(float2));
    size_t o_normals = take((size_t)N_PART * sizeof(float2));
    size_t base_need = off;

    char* ws = (char*)d_ws;

    if (ws_size >= base_need) {
        float2* fac     = (float2*)(ws + o_fac);
        float2* normals = (float2*)(ws + o_normals);

        prep_zero<<<(N_PART + 255) / 256, 256, 0, stream>>>(
            areas, dens, rest, fac, normals, (float2*)out);

        const int nthreads = N_EDGE / 8;                  // 800000
        const int nblocks  = (nthreads + 255) / 256;      // 3125
        flat_pass1<<<nblocks, 256, 0, stream>>>(
            nb, fac, q, dist, (float*)normals);
        flat_pass2<<<nblocks, 256, 0, stream>>>(
            nb, fac, q, dist, normals, out);
        return;
    }

    // --- Minimal fallback (needs only 800 KB for normals) ---
    float* normals = (float*)d_ws;
    const int nv = 2 * N_PART;
    fb_zero2<<<(nv + 255) / 256, 256, 0, stream>>>(normals, out, nv);
    const int blocks = (N_EDGE + 255) / 256;
    fb_pass1_atomic<<<blocks, 256, 0, stream>>>(
        nb, areas, dens, q, (const float2*)dist, normals);
    fb_pass2_atomic<<<blocks, 256, 0, stream>>>(
        nb, areas, rest, q, (const float2*)dist, (const float2*)normals, out);
}

// Round 6
// 366.484 us; speedup vs baseline: 3.8084x; 3.8084x over previous
//
#include <hip/hip_runtime.h>

// Problem constants (from reference)
constexpr int N_PART = 100000;
constexpr int N_EDGE = 6400000;
constexpr float SUPPORT = 0.05f;
constexpr float PI_F = 3.14159265358979323846f;

// ===========================================================================
// R6: return to the proven R1 architecture (374 us) with one surgical change:
// l1_sort records are AoS float4 (one ds_write_b128 scatter + one
// ds_read_b128 walk per edge) instead of SoA 4x ds_write_b32/ds_read_b32.
// Cost model (fitted R1-R5): divergent LDS atomic ~4 cyc/lane; divergent L2
// gather ~1 cyc/lane; global fp atomics write through to HBM (~10x worse,
// R5); occupancy irrelevant (shared LDS pipe). LDS op COUNT is the currency.
// ===========================================================================
constexpr int CH_LOG2 = 12;
constexpr int CH      = 1 << CH_LOG2;            // 4096 edges per sort chunk
constexpr int NCH     = (N_EDGE + CH - 1) / CH;  // 1563 chunks
constexpr int BIN_LOG2 = 12;
constexpr int BINSZ   = 1 << BIN_LOG2;           // 4096 particles per bin
constexpr int NBIN    = (N_PART + BINSZ - 1) / BINSZ;  // 25 bins
constexpr int BT_STRIDE = 32;                    // btab row stride (u32)
constexpr int G_MAX   = 40;                      // max accumulation groups
constexpr int ST_NW   = 8;                       // l1_sort waves (512 threads)
constexpr int MAXC    = 272;                     // max chunks per acc block (G>=6)

// --- Prep: per-particle factors (one 8 B gather in l1_sort phase 3).
__global__ __launch_bounds__(512) void prep_fac(
    const float* __restrict__ areas,
    const float* __restrict__ dens,
    const float* __restrict__ rest,
    float2* __restrict__ fac)
{
    int p = blockIdx.x * blockDim.x + threadIdx.x;
    if (p < N_PART)
        fac[p] = make_float2(areas[p] / dens[p], areas[p] * rest[p]);
}

// --- Level 1: per-chunk counting sort + payload precompute.
// AoS rec[CH] float4 {packbits, q, dx, dy}: scatter = ONE ds_write_b128,
// walk = ONE ds_read_b128 (R1 paid 4x b32 each way).
// Ranking via per-(wave,bin) LDS atomic cursor (R1-proven; ballot was slower).
// Output (per chunk, bin-grouped): pack = (i_loc12 << 17) | j17,
// pay1 = s*d, pay2 = fc*kern*d.  btab[t*32+b] = segment start; [NBIN] = len.
__global__ __launch_bounds__(512) void l1_sort(
    const int* __restrict__ nb,        // [2*E]
    const float2* __restrict__ fac,    // [N] (areas/dens, areas*rest)
    const float* __restrict__ q,       // [E]
    const float2* __restrict__ dist,   // [E,2]
    unsigned* __restrict__ gpack,
    float2* __restrict__ gpay1,
    float2* __restrict__ gpay2,
    unsigned* __restrict__ btab)       // [NCH*BT_STRIDE] u32
{
    __shared__ float4   rec[CH];              // 64 KB AoS, 16 B aligned
    __shared__ unsigned hist[ST_NW * NBIN];
    __shared__ unsigned curw[ST_NW * NBIN];
    __shared__ unsigned base[NBIN + 1];
    __shared__ unsigned bcnt[NBIN];

    const int t   = blockIdx.x;
    const int c0  = t * CH;
    const int len = min(CH, N_EDGE - c0);
    const int tid = threadIdx.x;
    const int wid = tid >> 6;                 // 8 waves

    for (int k = tid; k < ST_NW * NBIN; k += 512) hist[k] = 0u;

    // Phase 1: single coalesced sweep, everything into registers
    unsigned iv[8], jv[8];
    float    qv[8], dxv[8], dyv[8];
    #pragma unroll
    for (int k = 0; k < 8; ++k) {
        int idx = tid + k * 512;
        if (idx < len) {
            iv[k] = (unsigned)nb[c0 + idx];
            jv[k] = (unsigned)nb[N_EDGE + c0 + idx];
            qv[k] = q[c0 + idx];
            float2 d = dist[c0 + idx];
            dxv[k] = d.x;
            dyv[k] = d.y;
        }
    }
    __syncthreads();    // hist zeros visible

    #pragma unroll
    for (int k = 0; k < 8; ++k) {
        int idx = tid + k * 512;
        if (idx < len)
            atomicAdd(&hist[wid * NBIN + (iv[k] >> BIN_LOG2)], 1u);
    }
    __syncthreads();

    // Hierarchical scan: NBIN threads x 8 waves, then 1 x NBIN, then wide add
    if (tid < NBIN) {
        unsigned run = 0;
        for (int w = 0; w < ST_NW; ++w) {
            curw[w * NBIN + tid] = run;       // local (within-bin) offset
            run += hist[w * NBIN + tid];
        }
        bcnt[tid] = run;                      // per-bin total
    }
    __syncthreads();
    if (tid == 0) {
        unsigned run = 0;
        for (int b = 0; b < NBIN; ++b) { base[b] = run; run += bcnt[b]; }
        base[NBIN] = run;                     // == len
    }
    __syncthreads();
    if (tid < ST_NW * NBIN) curw[tid] += base[tid % NBIN];
    if (tid < NBIN)  btab[t * BT_STRIDE + tid]  = base[tid];
    if (tid == NBIN) btab[t * BT_STRIDE + NBIN] = (unsigned)len;
    __syncthreads();    // curw ready before ranking atomics

    // Phase 2: single ds_write_b128 scatter per edge; rank via wave cursor.
    #pragma unroll
    for (int k = 0; k < 8; ++k) {
        int idx = tid + k * 512;
        if (idx < len) {
            unsigned i   = iv[k];
            unsigned bin = i >> BIN_LOG2;
            unsigned r = atomicAdd(&curw[wid * NBIN + bin], 1u) & (CH - 1);
            unsigned pk = ((i & (BINSZ - 1)) << 17) | jv[k];
            rec[r] = make_float4(__uint_as_float(pk), qv[k], dxv[k], dyv[k]);
        }
    }
    __syncthreads();

    // Phase 3: walk sorted positions (ds_read_b128); single L2-resident
    // float2 gather fac[j]; write everything coalesced.
    const float Cw = 7.0f / (PI_F * SUPPORT * SUPPORT);
    for (int p = tid; p < len; p += 512) {
        float4 v = rec[p];
        unsigned pack = __float_as_uint(v.x);
        float qq = v.y;
        float dx = v.z, dy = v.w;
        unsigned j = pack & 0x1FFFFu;
        float2 f = fac[j];

        // pass-1 payload: SUPPORT * (areas[j]/dens[j]) * dWdq(q)
        float omq  = fmaxf(1.0f - qq, 0.0f);
        float dWdq = Cw * (-20.0f * qq * omq * omq * omq) * (1.0f / SUPPORT);
        float s    = SUPPORT * f.x * dWdq;

        // cohesion payload: areas[j]*rest[j]*kern(q)  (net sign +)
        float qm1  = qq - 1.0f;
        float tt   = qm1 * qm1 * qm1 * qq * qq * qq;
        float kern = (qq <= 0.5f) ? fmaf(128.0f, tt, 1.0f) : 64.0f * tt;
        float fc   = f.y * kern;

        int o = c0 + p;
        gpack[o] = pack;
        gpay1[o] = make_float2(s * dx, s * dy);
        gpay2[o] = make_float2(fc * dx, fc * dy);
    }
}

// --- Pass B: accumulate normals per bin; LDS tile + partials store (no
// global atomics). 32 KB acc -> 4 blocks/CU. btab preloaded. Unroll x4
// (pure load->atomic body: deep MLP hides stream latency under atomics).
__global__ __launch_bounds__(512) void passB(
    const unsigned* __restrict__ btab,
    const unsigned* __restrict__ gpack,
    const float2* __restrict__ gpay1,
    float2* __restrict__ partials,       // [G][NBIN*BINSZ]
    int G)
{
    __shared__ float accx[BINSZ];        // 16 KB
    __shared__ float accy[BINSZ];        // 16 KB
    __shared__ unsigned s_sb[MAXC], s_se[MAXC];
    const int b = blockIdx.x % NBIN;
    const int g = blockIdx.x / NBIN;
    const int wave = threadIdx.x >> 6;
    const int lane = threadIdx.x & 63;

    const int t0 = (int)((long long)g * NCH / G);
    const int t1 = (int)((long long)(g + 1) * NCH / G);
    const int nt = t1 - t0;

    for (int k = threadIdx.x; k < BINSZ; k += 512) { accx[k] = 0.0f; accy[k] = 0.0f; }
    for (int c = threadIdx.x; c < nt; c += 512) {
        s_sb[c] = btab[(t0 + c) * BT_STRIDE + b];
        s_se[c] = btab[(t0 + c) * BT_STRIDE + b + 1];
    }
    __syncthreads();

    for (int c = wave; c < nt; c += 8) {
        const int c0  = (t0 + c) * CH;
        unsigned sb = s_sb[c], se = s_se[c];
        unsigned k = sb + lane;
        for (; k + 192 < se; k += 256) {
            int o0 = c0 + (int)k;
            unsigned pk0 = gpack[o0], pk1 = gpack[o0 + 64],
                     pk2 = gpack[o0 + 128], pk3 = gpack[o0 + 192];
            float2 p0 = gpay1[o0],       p1 = gpay1[o0 + 64],
                   p2 = gpay1[o0 + 128], p3 = gpay1[o0 + 192];
            unsigned l0 = (pk0 >> 17) & (BINSZ - 1);
            unsigned l1 = (pk1 >> 17) & (BINSZ - 1);
            unsigned l2 = (pk2 >> 17) & (BINSZ - 1);
            unsigned l3 = (pk3 >> 17) & (BINSZ - 1);
            atomicAdd(&accx[l0], p0.x);  atomicAdd(&accy[l0], p0.y);
            atomicAdd(&accx[l1], p1.x);  atomicAdd(&accy[l1], p1.y);
            atomicAdd(&accx[l2], p2.x);  atomicAdd(&accy[l2], p2.y);
            atomicAdd(&accx[l3], p3.x);  atomicAdd(&accy[l3], p3.y);
        }
        for (; k < se; k += 64) {
            int o = c0 + (int)k;
            unsigned pk = gpack[o];
            float2 p = gpay1[o];
            unsigned loc = (pk >> 17) & (BINSZ - 1);
            atomicAdd(&accx[loc], p.x);
            atomicAdd(&accy[loc], p.y);
        }
    }
    __syncthreads();

    float2* __restrict__ dst = partials + (size_t)g * (NBIN * BINSZ) + (size_t)b * BINSZ;
    for (int k = threadIdx.x; k < BINSZ; k += 512)
        dst[k] = make_float2(accx[k], accy[k]);
}

// --- Pass D: acc_i += (n_j - n_i + coh) per edge; LDS tile + partials store.
__global__ __launch_bounds__(512) void passD(
    const unsigned* __restrict__ btab,
    const unsigned* __restrict__ gpack,
    const float2* __restrict__ gpay2,
    const float2* __restrict__ normals,  // [N] complete
    float2* __restrict__ partials,
    int G)
{
    __shared__ float accx[BINSZ];
    __shared__ float accy[BINSZ];
    __shared__ unsigned s_sb[MAXC], s_se[MAXC];
    const int b = blockIdx.x % NBIN;
    const int g = blockIdx.x / NBIN;
    const int wave = threadIdx.x >> 6;
    const int lane = threadIdx.x & 63;

    const int t0 = (int)((long long)g * NCH / G);
    const int t1 = (int)((long long)(g + 1) * NCH / G);
    const int nt = t1 - t0;

    for (int k = threadIdx.x; k < BINSZ; k += 512) { accx[k] = 0.0f; accy[k] = 0.0f; }
    for (int c = threadIdx.x; c < nt; c += 512) {
        s_sb[c] = btab[(t0 + c) * BT_STRIDE + b];
        s_se[c] = btab[(t0 + c) * BT_STRIDE + b + 1];
    }
    __syncthreads();

    const int gbase = b * BINSZ;
    for (int c = wave; c < nt; c += 8) {
        const int c0  = (t0 + c) * CH;
        unsigned sb = s_sb[c], se = s_se[c];
        unsigned k = sb + lane;
        for (; k + 64 < se; k += 128) {
            int o0 = c0 + (int)k, o1 = o0 + 64;
            unsigned pk0 = gpack[o0], pk1 = gpack[o1];
            float2 h0 = gpay2[o0], h1 = gpay2[o1];
            unsigned j0 = min(pk0 & 0x1FFFFu, (unsigned)(N_PART - 1));
            unsigned j1 = min(pk1 & 0x1FFFFu, (unsigned)(N_PART - 1));
            unsigned l0 = (pk0 >> 17) & (BINSZ - 1);
            unsigned l1 = (pk1 >> 17) & (BINSZ - 1);
            unsigned i0 = min((unsigned)(gbase + l0), (unsigned)(N_PART - 1));
            unsigned i1 = min((unsigned)(gbase + l1), (unsigned)(N_PART - 1));
            float2 nj0 = normals[j0];
            float2 nj1 = normals[j1];
            float2 ni0 = normals[i0];          // hot 32 KB window
            float2 ni1 = normals[i1];
            atomicAdd(&accx[l0], nj0.x - ni0.x + h0.x);
            atomicAdd(&accy[l0], nj0.y - ni0.y + h0.y);
            atomicAdd(&accx[l1], nj1.x - ni1.x + h1.x);
            atomicAdd(&accy[l1], nj1.y - ni1.y + h1.y);
        }
        if (k < se) {
            int o = c0 + (int)k;
            unsigned pk = gpack[o];
            float2 coh = gpay2[o];
            unsigned j   = min(pk & 0x1FFFFu, (unsigned)(N_PART - 1));
            unsigned loc = (pk >> 17) & (BINSZ - 1);
            unsigned ii  = min((unsigned)(gbase + loc), (unsigned)(N_PART - 1));
            float2 nj = normals[j];
            float2 ni = normals[ii];
            atomicAdd(&accx[loc], nj.x - ni.x + coh.x);
            atomicAdd(&accy[loc], nj.y - ni.y + coh.y);
        }
    }
    __syncthreads();

    float2* __restrict__ dst = partials + (size_t)g * (NBIN * BINSZ) + (size_t)b * BINSZ;
    for (int k = threadIdx.x; k < BINSZ; k += 512)
        dst[k] = make_float2(accx[k], accy[k]);
}

// dst[p] = sum_g partials[g][p]
__global__ __launch_bounds__(256) void reduceG(
    const float2* __restrict__ partials, float2* __restrict__ dst, int G)
{
    int p = blockIdx.x * blockDim.x + threadIdx.x;
    if (p >= N_PART) return;
    float ax = 0.0f, ay = 0.0f;
    for (int g = 0; g < G; ++g) {
        float2 v = partials[(size_t)g * (NBIN * BINSZ) + p];
        ax += v.x; ay += v.y;
    }
    dst[p] = make_float2(ax, ay);
}

// ===========================================================================
// Fallback 1: binned multi-read path. Fallback 2: atomics.
// ===========================================================================
constexpr int FB_BSZ_LOG2 = 13;
constexpr int FB_BSZ   = 1 << FB_BSZ_LOG2;
constexpr int FB_NBINS = (N_PART + FB_BSZ - 1) / FB_BSZ;
constexpr int FB_NP_PAD = FB_NBINS * FB_BSZ;
constexpr int FB_C_TARGET = 39;

__global__ __launch_bounds__(1024) void fb_pass1_binned(
    const int* __restrict__ nb, const float* __restrict__ areas,
    const float* __restrict__ dens, const float* __restrict__ q,
    const float2* __restrict__ dist, float* __restrict__ partials, int C)
{
    __shared__ float lds[2 * FB_BSZ];
    const int b = blockIdx.x % FB_NBINS;
    const int c = blockIdx.x / FB_NBINS;
    for (int k = threadIdx.x; k < 2 * FB_BSZ; k += blockDim.x) lds[k] = 0.0f;
    __syncthreads();
    const int start = (int)((long long)c       * (N_EDGE / 4) / C) * 4;
    const int end   = (int)((long long)(c + 1) * (N_EDGE / 4) / C) * 4;
    const int4* __restrict__ nb4 = (const int4*)nb;
    const float Cw = 7.0f / (PI_F * SUPPORT * SUPPORT);
    for (int e = start + (int)threadIdx.x * 4; e < end; e += (int)blockDim.x * 4) {
        int4 iq = nb4[e >> 2];
        #pragma unroll
        for (int k = 0; k < 4; ++k) {
            int iv = (k == 0) ? iq.x : (k == 1) ? iq.y : (k == 2) ? iq.z : iq.w;
            if ((iv >> FB_BSZ_LOG2) == b) {
                int ee = e + k;
                int j  = nb[N_EDGE + ee];
                float qq  = q[ee];
                float fac = areas[j] / dens[j];
                float omq  = fmaxf(1.0f - qq, 0.0f);
                float dWdq = Cw * (-20.0f * qq * omq * omq * omq) * (1.0f / SUPPORT);
                float s = SUPPORT * fac * dWdq;
                float2 d = dist[ee];
                int loc = (iv & (FB_BSZ - 1)) << 1;
                atomicAdd(&lds[loc],     s * d.x);
                atomicAdd(&lds[loc + 1], s * d.y);
            }
        }
    }
    __syncthreads();
    float2* __restrict__ dst = (float2*)partials + (size_t)c * FB_NP_PAD + (size_t)b * FB_BSZ;
    const float2* __restrict__ src = (const float2*)lds;
    for (int k = threadIdx.x; k < FB_BSZ; k += blockDim.x) dst[k] = src[k];
}

__global__ __launch_bounds__(1024) void fb_pass2_binned(
    const int* __restrict__ nb, const float* __restrict__ areas,
    const float* __restrict__ rest, const float* __restrict__ q,
    const float2* __restrict__ dist, const float2* __restrict__ normals,
    float* __restrict__ partials, int C)
{
    __shared__ float lds[2 * FB_BSZ];
    const int b = blockIdx.x % FB_NBINS;
    const int c = blockIdx.x / FB_NBINS;
    for (int k = threadIdx.x; k < 2 * FB_BSZ; k += blockDim.x) lds[k] = 0.0f;
    __syncthreads();
    const int start = (int)((long long)c       * (N_EDGE / 4) / C) * 4;
    const int end   = (int)((long long)(c + 1) * (N_EDGE / 4) / C) * 4;
    const int4* __restrict__ nb4 = (const int4*)nb;
    for (int e = start + (int)threadIdx.x * 4; e < end; e += (int)blockDim.x * 4) {
        int4 iq = nb4[e >> 2];
        #pragma unroll
        for (int k = 0; k < 4; ++k) {
            int iv = (k == 0) ? iq.x : (k == 1) ? iq.y : (k == 2) ? iq.z : iq.w;
            if ((iv >> FB_BSZ_LOG2) == b) {
                int ee = e + k;
                int j  = nb[N_EDGE + ee];
                float2 ni = normals[iv];
                float2 nj = normals[j];
                float qq  = q[ee];
                float fc  = areas[j] * rest[j];
                float qm1 = qq - 1.0f;
                float t   = qm1 * qm1 * qm1 * qq * qq * qq;
                float kern = (qq <= 0.5f) ? fmaf(128.0f, t, 1.0f) : 64.0f * t;
                float2 d = dist[ee];
                int loc = (iv & (FB_BSZ - 1)) << 1;
                atomicAdd(&lds[loc],     -(ni.x - nj.x) + fc * kern * d.x);
                atomicAdd(&lds[loc + 1], -(ni.y - nj.y) + fc * kern * d.y);
            }
        }
    }
    __syncthreads();
    float2* __restrict__ dst = (float2*)partials + (size_t)c * FB_NP_PAD + (size_t)b * FB_BSZ;
    const float2* __restrict__ src = (const float2*)lds;
    for (int k = threadIdx.x; k < FB_BSZ; k += blockDim.x) dst[k] = src[k];
}

__global__ __launch_bounds__(256) void fb_reduce_partials(
    const float* __restrict__ partials, float* __restrict__ dst, int C)
{
    int p = blockIdx.x * blockDim.x + threadIdx.x;
    if (p >= N_PART) return;
    const float2* __restrict__ p2 = (const float2*)partials;
    float ax = 0.0f, ay = 0.0f;
    for (int c = 0; c < C; ++c) {
        float2 v = p2[(size_t)c * FB_NP_PAD + p];
        ax += v.x; ay += v.y;
    }
    ((float2*)dst)[p] = make_float2(ax, ay);
}

__global__ __launch_bounds__(256) void fb_zero2(float* __restrict__ a,
                                                float* __restrict__ b, int n) {
    int idx = blockIdx.x * blockDim.x + threadIdx.x;
    if (idx < n) { a[idx] = 0.0f; b[idx] = 0.0f; }
}

__global__ __launch_bounds__(256) void fb_pass1_atomic(
    const int* __restrict__ nb, const float* __restrict__ areas,
    const float* __restrict__ dens, const float* __restrict__ q,
    const float2* __restrict__ dist, float* __restrict__ normals)
{
    int e = blockIdx.x * blockDim.x + threadIdx.x;
    if (e >= N_EDGE) return;
    int i = nb[e];
    int j = nb[N_EDGE + e];
    float qq  = q[e];
    float fac = areas[j] / dens[j];
    const float Cw = 7.0f / (PI_F * SUPPORT * SUPPORT);
    float omq  = fmaxf(1.0f - qq, 0.0f);
    float dWdq = Cw * (-20.0f * qq * omq * omq * omq) * (1.0f / SUPPORT);
    float s = SUPPORT * fac * dWdq;
    float2 d = dist[e];
    atomicAdd(&normals[2 * i],     s * d.x);
    atomicAdd(&normals[2 * i + 1], s * d.y);
}

__global__ __launch_bounds__(256) void fb_pass2_atomic(
    const int* __restrict__ nb, const float* __restrict__ areas,
    const float* __restrict__ rest, const float* __restrict__ q,
    const float2* __restrict__ dist, const float2* __restrict__ normals,
    float* __restrict__ out)
{
    int e = blockIdx.x * blockDim.x + threadIdx.x;
    if (e >= N_EDGE) return;
    int i = nb[e];
    int j = nb[N_EDGE + e];
    float2 ni = normals[i];
    float2 nj = normals[j];
    float qq  = q[e];
    float fc  = areas[j] * rest[j];
    float qm1 = qq - 1.0f;
    float t   = qm1 * qm1 * qm1 * qq * qq * qq;
    float kern = (qq <= 0.5f) ? fmaf(128.0f, t, 1.0f) : 64.0f * t;
    float2 d = dist[e];
    atomicAdd(&out[2 * i],     -(ni.x - nj.x) + fc * kern * d.x);
    atomicAdd(&out[2 * i + 1], -(ni.y - nj.y) + fc * kern * d.y);
}

// ===========================================================================
extern "C" void kernel_launch(void* const* d_in, const int* in_sizes, int n_in,
                              void* d_out, int out_size, void* d_ws, size_t ws_size,
                              hipStream_t stream) {
    const int*   nb    = (const int*)d_in[0];     // [2*E]
    const float* areas = (const float*)d_in[1];   // [N]
    const float* dens  = (const float*)d_in[2];   // [N]
    const float* rest  = (const float*)d_in[3];   // [N]
    const float* q     = (const float*)d_in[4];   // [E]
    const float* dist  = (const float*)d_in[5];   // [E,2]
    float* out = (float*)d_out;                   // [N,2]

    // --- Sorted-path workspace layout ---
    size_t off = 0;
    auto take = [&](size_t bytes) { size_t o = off; off += (bytes + 255) & ~(size_t)255; return o; };
    size_t o_pack    = take((size_t)N_EDGE * sizeof(unsigned));
    size_t o_pay1    = take((size_t)N_EDGE * sizeof(float2));
    size_t o_pay2    = take((size_t)N_EDGE * sizeof(float2));
    size_t o_btab    = take((size_t)NCH * BT_STRIDE * sizeof(unsigned));
    size_t o_normals = take((size_t)N_PART * sizeof(float2));
    size_t o_fac     = take((size_t)N_PART * sizeof(float2));
    size_t base_need = off;
    const size_t per_g = (size_t)(NBIN * BINSZ) * sizeof(float2);

    int G = 0;
    if (ws_size > base_need) {
        G = (int)((ws_size - base_need) / per_g);
        if (G > G_MAX) G = G_MAX;
    }

    char* ws = (char*)d_ws;

    if (G >= 6) {
        unsigned* gpack   = (unsigned*)(ws + o_pack);
        float2*   gpay1   = (float2*)(ws + o_pay1);
        float2*   gpay2   = (float2*)(ws + o_pay2);
        unsigned* btab    = (unsigned*)(ws + o_btab);
        float2*   normals = (float2*)(ws + o_normals);
        float2*   fac     = (float2*)(ws + o_fac);
        float2*   partials= (float2*)(ws + base_need);

        prep_fac<<<(N_PART + 511) / 512, 512, 0, stream>>>(areas, dens, rest, fac);
        l1_sort<<<NCH, 512, 0, stream>>>(
            nb, fac, q, (const float2*)dist,
            gpack, gpay1, gpay2, btab);
        passB<<<NBIN * G, 512, 0, stream>>>(btab, gpack, gpay1, partials, G);
        reduceG<<<(N_PART + 255) / 256, 256, 0, stream>>>(partials, normals, G);
        passD<<<NBIN * G, 512, 0, stream>>>(btab, gpack, gpay2, normals, partials, G);
        reduceG<<<(N_PART + 255) / 256, 256, 0, stream>>>(partials, (float2*)out, G);
        return;
    }

    // --- Fallback paths ---
    const size_t normals_pad = 1 << 20;
    float* normals  = (float*)d_ws;
    float* partials = (float*)((char*)d_ws + normals_pad);
    const size_t per_chunk = (size_t)FB_NP_PAD * 2 * sizeof(float);
    int C = 0;
    if (ws_size > normals_pad) {
        C = (int)((ws_size - normals_pad) / per_chunk);
        if (C > FB_C_TARGET) C = FB_C_TARGET;
    }

    if (C >= 4) {
        const int grid = FB_NBINS * C;
        fb_pass1_binned<<<grid, 1024, 0, stream>>>(
            nb, areas, dens, q, (const float2*)dist, partials, C);
        fb_reduce_partials<<<(N_PART + 255) / 256, 256, 0, stream>>>(partials, normals, C);
        fb_pass2_binned<<<grid, 1024, 0, stream>>>(
            nb, areas, rest, q, (const float2*)dist, (const float2*)normals, partials, C);
        fb_reduce_partials<<<(N_PART + 255) / 256, 256, 0, stream>>>(partials, out, C);
    } else {
        const int nv = 2 * N_PART;
        fb_zero2<<<(nv + 255) / 256, 256, 0, stream>>>(normals, out, nv);
        const int blocks = (N_EDGE + 255) / 256;
        fb_pass1_atomic<<<blocks, 256, 0, stream>>>(
            nb, areas, dens, q, (const float2*)dist, normals);
        fb_pass2_atomic<<<blocks, 256, 0, stream>>>(
            nb, areas, rest, q, (const float2*)dist, (const float2*)normals, out);
    }
}

// Round 7
// 364.731 us; speedup vs baseline: 3.8267x; 1.0048x over previous
//
#include <hip/hip_runtime.h>

// Problem constants (from reference)
constexpr int N_PART = 100000;
constexpr int N_EDGE = 6400000;
constexpr float SUPPORT = 0.05f;
constexpr float PI_F = 3.14159265358979323846f;

// ===========================================================================
// R7: identical to R6 (366 us, best) except passB/passD LDS fp32 accumulator
// atomics use unsafeAtomicAdd -> native ds_add_f32.
// Evidence: R5 proved global atomicAdd(float) lowers to a CAS loop without
// -munsafe-fp-atomics; derived-throughput math (ds ~5.8cyc/wave, conflicts
// ~N/2.8) says native LDS atomics should cost ~10us/pass, measured 85-90us
// -> 8x anomaly consistent with an LDS CAS loop too. Integer LDS atomics
// (l1_sort hist/curw) are native ds_add_u32 and l1_sort is NOT atomic-bound,
// consistent.
// ===========================================================================
constexpr int CH_LOG2 = 12;
constexpr int CH      = 1 << CH_LOG2;            // 4096 edges per sort chunk
constexpr int NCH     = (N_EDGE + CH - 1) / CH;  // 1563 chunks
constexpr int BIN_LOG2 = 12;
constexpr int BINSZ   = 1 << BIN_LOG2;           // 4096 particles per bin
constexpr int NBIN    = (N_PART + BINSZ - 1) / BINSZ;  // 25 bins
constexpr int BT_STRIDE = 32;                    // btab row stride (u32)
constexpr int G_MAX   = 40;                      // max accumulation groups
constexpr int ST_NW   = 8;                       // l1_sort waves (512 threads)
constexpr int MAXC    = 272;                     // max chunks per acc block (G>=6)

// Native fp32 atomic add (ds_add_f32 for LDS, global_atomic_add_f32 for
// global). Default atomicAdd(float*) lowers to a CAS retry loop without
// -munsafe-fp-atomics — ~8x the pipe cost for divergent LDS accumulation.
__device__ __forceinline__ void lAdd(float* p, float v) {
#if defined(__HIP_PLATFORM_AMD__) || defined(__HIP_PLATFORM_HCC__)
    unsafeAtomicAdd(p, v);
#else
    atomicAdd(p, v);
#endif
}

// --- Prep: per-particle factors (one 8 B gather in l1_sort phase 3).
__global__ __launch_bounds__(512) void prep_fac(
    const float* __restrict__ areas,
    const float* __restrict__ dens,
    const float* __restrict__ rest,
    float2* __restrict__ fac)
{
    int p = blockIdx.x * blockDim.x + threadIdx.x;
    if (p < N_PART)
        fac[p] = make_float2(areas[p] / dens[p], areas[p] * rest[p]);
}

// --- Level 1: per-chunk counting sort + payload precompute.
// AoS rec[CH] float4 {packbits, q, dx, dy}: scatter = ONE ds_write_b128,
// walk = ONE ds_read_b128. Ranking via per-(wave,bin) native u32 cursor.
// Output (per chunk, bin-grouped): pack = (i_loc12 << 17) | j17,
// pay1 = s*d, pay2 = fc*kern*d.  btab[t*32+b] = segment start; [NBIN] = len.
__global__ __launch_bounds__(512) void l1_sort(
    const int* __restrict__ nb,        // [2*E]
    const float2* __restrict__ fac,    // [N] (areas/dens, areas*rest)
    const float* __restrict__ q,       // [E]
    const float2* __restrict__ dist,   // [E,2]
    unsigned* __restrict__ gpack,
    float2* __restrict__ gpay1,
    float2* __restrict__ gpay2,
    unsigned* __restrict__ btab)       // [NCH*BT_STRIDE] u32
{
    __shared__ float4   rec[CH];              // 64 KB AoS, 16 B aligned
    __shared__ unsigned hist[ST_NW * NBIN];
    __shared__ unsigned curw[ST_NW * NBIN];
    __shared__ unsigned base[NBIN + 1];
    __shared__ unsigned bcnt[NBIN];

    const int t   = blockIdx.x;
    const int c0  = t * CH;
    const int len = min(CH, N_EDGE - c0);
    const int tid = threadIdx.x;
    const int wid = tid >> 6;                 // 8 waves

    for (int k = tid; k < ST_NW * NBIN; k += 512) hist[k] = 0u;

    // Phase 1: single coalesced sweep, everything into registers
    unsigned iv[8], jv[8];
    float    qv[8], dxv[8], dyv[8];
    #pragma unroll
    for (int k = 0; k < 8; ++k) {
        int idx = tid + k * 512;
        if (idx < len) {
            iv[k] = (unsigned)nb[c0 + idx];
            jv[k] = (unsigned)nb[N_EDGE + c0 + idx];
            qv[k] = q[c0 + idx];
            float2 d = dist[c0 + idx];
            dxv[k] = d.x;
            dyv[k] = d.y;
        }
    }
    __syncthreads();    // hist zeros visible

    #pragma unroll
    for (int k = 0; k < 8; ++k) {
        int idx = tid + k * 512;
        if (idx < len)
            atomicAdd(&hist[wid * NBIN + (iv[k] >> BIN_LOG2)], 1u);
    }
    __syncthreads();

    // Hierarchical scan: NBIN threads x 8 waves, then 1 x NBIN, then wide add
    if (tid < NBIN) {
        unsigned run = 0;
        for (int w = 0; w < ST_NW; ++w) {
            curw[w * NBIN + tid] = run;       // local (within-bin) offset
            run += hist[w * NBIN + tid];
        }
        bcnt[tid] = run;                      // per-bin total
    }
    __syncthreads();
    if (tid == 0) {
        unsigned run = 0;
        for (int b = 0; b < NBIN; ++b) { base[b] = run; run += bcnt[b]; }
        base[NBIN] = run;                     // == len
    }
    __syncthreads();
    if (tid < ST_NW * NBIN) curw[tid] += base[tid % NBIN];
    if (tid < NBIN)  btab[t * BT_STRIDE + tid]  = base[tid];
    if (tid == NBIN) btab[t * BT_STRIDE + NBIN] = (unsigned)len;
    __syncthreads();    // curw ready before ranking atomics

    // Phase 2: single ds_write_b128 scatter per edge; rank via wave cursor.
    #pragma unroll
    for (int k = 0; k < 8; ++k) {
        int idx = tid + k * 512;
        if (idx < len) {
            unsigned i   = iv[k];
            unsigned bin = i >> BIN_LOG2;
            unsigned r = atomicAdd(&curw[wid * NBIN + bin], 1u) & (CH - 1);
            unsigned pk = ((i & (BINSZ - 1)) << 17) | jv[k];
            rec[r] = make_float4(__uint_as_float(pk), qv[k], dxv[k], dyv[k]);
        }
    }
    __syncthreads();

    // Phase 3: walk sorted positions (ds_read_b128); single L2-resident
    // float2 gather fac[j]; write everything coalesced.
    const float Cw = 7.0f / (PI_F * SUPPORT * SUPPORT);
    for (int p = tid; p < len; p += 512) {
        float4 v = rec[p];
        unsigned pack = __float_as_uint(v.x);
        float qq = v.y;
        float dx = v.z, dy = v.w;
        unsigned j = pack & 0x1FFFFu;
        float2 f = fac[j];

        // pass-1 payload: SUPPORT * (areas[j]/dens[j]) * dWdq(q)
        float omq  = fmaxf(1.0f - qq, 0.0f);
        float dWdq = Cw * (-20.0f * qq * omq * omq * omq) * (1.0f / SUPPORT);
        float s    = SUPPORT * f.x * dWdq;

        // cohesion payload: areas[j]*rest[j]*kern(q)  (net sign +)
        float qm1  = qq - 1.0f;
        float tt   = qm1 * qm1 * qm1 * qq * qq * qq;
        float kern = (qq <= 0.5f) ? fmaf(128.0f, tt, 1.0f) : 64.0f * tt;
        float fc   = f.y * kern;

        int o = c0 + p;
        gpack[o] = pack;
        gpay1[o] = make_float2(s * dx, s * dy);
        gpay2[o] = make_float2(fc * dx, fc * dy);
    }
}

// --- Pass B: accumulate normals per bin; LDS tile (native ds_add_f32) +
// partials store. 32 KB acc -> 4 blocks/CU. btab preloaded. Unroll x4.
__global__ __launch_bounds__(512) void passB(
    const unsigned* __restrict__ btab,
    const unsigned* __restrict__ gpack,
    const float2* __restrict__ gpay1,
    float2* __restrict__ partials,       // [G][NBIN*BINSZ]
    int G)
{
    __shared__ float accx[BINSZ];        // 16 KB
    __shared__ float accy[BINSZ];        // 16 KB
    __shared__ unsigned s_sb[MAXC], s_se[MAXC];
    const int b = blockIdx.x % NBIN;
    const int g = blockIdx.x / NBIN;
    const int wave = threadIdx.x >> 6;
    const int lane = threadIdx.x & 63;

    const int t0 = (int)((long long)g * NCH / G);
    const int t1 = (int)((long long)(g + 1) * NCH / G);
    const int nt = t1 - t0;

    for (int k = threadIdx.x; k < BINSZ; k += 512) { accx[k] = 0.0f; accy[k] = 0.0f; }
    for (int c = threadIdx.x; c < nt; c += 512) {
        s_sb[c] = btab[(t0 + c) * BT_STRIDE + b];
        s_se[c] = btab[(t0 + c) * BT_STRIDE + b + 1];
    }
    __syncthreads();

    for (int c = wave; c < nt; c += 8) {
        const int c0  = (t0 + c) * CH;
        unsigned sb = s_sb[c], se = s_se[c];
        unsigned k = sb + lane;
        for (; k + 192 < se; k += 256) {
            int o0 = c0 + (int)k;
            unsigned pk0 = gpack[o0], pk1 = gpack[o0 + 64],
                     pk2 = gpack[o0 + 128], pk3 = gpack[o0 + 192];
            float2 p0 = gpay1[o0],       p1 = gpay1[o0 + 64],
                   p2 = gpay1[o0 + 128], p3 = gpay1[o0 + 192];
            unsigned l0 = (pk0 >> 17) & (BINSZ - 1);
            unsigned l1 = (pk1 >> 17) & (BINSZ - 1);
            unsigned l2 = (pk2 >> 17) & (BINSZ - 1);
            unsigned l3 = (pk3 >> 17) & (BINSZ - 1);
            lAdd(&accx[l0], p0.x);  lAdd(&accy[l0], p0.y);
            lAdd(&accx[l1], p1.x);  lAdd(&accy[l1], p1.y);
            lAdd(&accx[l2], p2.x);  lAdd(&accy[l2], p2.y);
            lAdd(&accx[l3], p3.x);  lAdd(&accy[l3], p3.y);
        }
        for (; k < se; k += 64) {
            int o = c0 + (int)k;
            unsigned pk = gpack[o];
            float2 p = gpay1[o];
            unsigned loc = (pk >> 17) & (BINSZ - 1);
            lAdd(&accx[loc], p.x);
            lAdd(&accy[loc], p.y);
        }
    }
    __syncthreads();

    float2* __restrict__ dst = partials + (size_t)g * (NBIN * BINSZ) + (size_t)b * BINSZ;
    for (int k = threadIdx.x; k < BINSZ; k += 512)
        dst[k] = make_float2(accx[k], accy[k]);
}

// --- Pass D: acc_i += (n_j - n_i + coh) per edge; LDS tile (native
// ds_add_f32) + partials store.
__global__ __launch_bounds__(512) void passD(
    const unsigned* __restrict__ btab,
    const unsigned* __restrict__ gpack,
    const float2* __restrict__ gpay2,
    const float2* __restrict__ normals,  // [N] complete
    float2* __restrict__ partials,
    int G)
{
    __shared__ float accx[BINSZ];
    __shared__ float accy[BINSZ];
    __shared__ unsigned s_sb[MAXC], s_se[MAXC];
    const int b = blockIdx.x % NBIN;
    const int g = blockIdx.x / NBIN;
    const int wave = threadIdx.x >> 6;
    const int lane = threadIdx.x & 63;

    const int t0 = (int)((long long)g * NCH / G);
    const int t1 = (int)((long long)(g + 1) * NCH / G);
    const int nt = t1 - t0;

    for (int k = threadIdx.x; k < BINSZ; k += 512) { accx[k] = 0.0f; accy[k] = 0.0f; }
    for (int c = threadIdx.x; c < nt; c += 512) {
        s_sb[c] = btab[(t0 + c) * BT_STRIDE + b];
        s_se[c] = btab[(t0 + c) * BT_STRIDE + b + 1];
    }
    __syncthreads();

    const int gbase = b * BINSZ;
    for (int c = wave; c < nt; c += 8) {
        const int c0  = (t0 + c) * CH;
        unsigned sb = s_sb[c], se = s_se[c];
        unsigned k = sb + lane;
        for (; k + 64 < se; k += 128) {
            int o0 = c0 + (int)k, o1 = o0 + 64;
            unsigned pk0 = gpack[o0], pk1 = gpack[o1];
            float2 h0 = gpay2[o0], h1 = gpay2[o1];
            unsigned j0 = min(pk0 & 0x1FFFFu, (unsigned)(N_PART - 1));
            unsigned j1 = min(pk1 & 0x1FFFFu, (unsigned)(N_PART - 1));
            unsigned l0 = (pk0 >> 17) & (BINSZ - 1);
            unsigned l1 = (pk1 >> 17) & (BINSZ - 1);
            unsigned i0 = min((unsigned)(gbase + l0), (unsigned)(N_PART - 1));
            unsigned i1 = min((unsigned)(gbase + l1), (unsigned)(N_PART - 1));
            float2 nj0 = normals[j0];
            float2 nj1 = normals[j1];
            float2 ni0 = normals[i0];          // hot 32 KB window
            float2 ni1 = normals[i1];
            lAdd(&accx[l0], nj0.x - ni0.x + h0.x);
            lAdd(&accy[l0], nj0.y - ni0.y + h0.y);
            lAdd(&accx[l1], nj1.x - ni1.x + h1.x);
            lAdd(&accy[l1], nj1.y - ni1.y + h1.y);
        }
        if (k < se) {
            int o = c0 + (int)k;
            unsigned pk = gpack[o];
            float2 coh = gpay2[o];
            unsigned j   = min(pk & 0x1FFFFu, (unsigned)(N_PART - 1));
            unsigned loc = (pk >> 17) & (BINSZ - 1);
            unsigned ii  = min((unsigned)(gbase + loc), (unsigned)(N_PART - 1));
            float2 nj = normals[j];
            float2 ni = normals[ii];
            lAdd(&accx[loc], nj.x - ni.x + coh.x);
            lAdd(&accy[loc], nj.y - ni.y + coh.y);
        }
    }
    __syncthreads();

    float2* __restrict__ dst = partials + (size_t)g * (NBIN * BINSZ) + (size_t)b * BINSZ;
    for (int k = threadIdx.x; k < BINSZ; k += 512)
        dst[k] = make_float2(accx[k], accy[k]);
}

// dst[p] = sum_g partials[g][p]
__global__ __launch_bounds__(256) void reduceG(
    const float2* __restrict__ partials, float2* __restrict__ dst, int G)
{
    int p = blockIdx.x * blockDim.x + threadIdx.x;
    if (p >= N_PART) return;
    float ax = 0.0f, ay = 0.0f;
    for (int g = 0; g < G; ++g) {
        float2 v = partials[(size_t)g * (NBIN * BINSZ) + p];
        ax += v.x; ay += v.y;
    }
    dst[p] = make_float2(ax, ay);
}

// ===========================================================================
// Fallback 1: binned multi-read path. Fallback 2: atomics.
// ===========================================================================
constexpr int FB_BSZ_LOG2 = 13;
constexpr int FB_BSZ   = 1 << FB_BSZ_LOG2;
constexpr int FB_NBINS = (N_PART + FB_BSZ - 1) / FB_BSZ;
constexpr int FB_NP_PAD = FB_NBINS * FB_BSZ;
constexpr int FB_C_TARGET = 39;

__global__ __launch_bounds__(1024) void fb_pass1_binned(
    const int* __restrict__ nb, const float* __restrict__ areas,
    const float* __restrict__ dens, const float* __restrict__ q,
    const float2* __restrict__ dist, float* __restrict__ partials, int C)
{
    __shared__ float lds[2 * FB_BSZ];
    const int b = blockIdx.x % FB_NBINS;
    const int c = blockIdx.x / FB_NBINS;
    for (int k = threadIdx.x; k < 2 * FB_BSZ; k += blockDim.x) lds[k] = 0.0f;
    __syncthreads();
    const int start = (int)((long long)c       * (N_EDGE / 4) / C) * 4;
    const int end   = (int)((long long)(c + 1) * (N_EDGE / 4) / C) * 4;
    const int4* __restrict__ nb4 = (const int4*)nb;
    const float Cw = 7.0f / (PI_F * SUPPORT * SUPPORT);
    for (int e = start + (int)threadIdx.x * 4; e < end; e += (int)blockDim.x * 4) {
        int4 iq = nb4[e >> 2];
        #pragma unroll
        for (int k = 0; k < 4; ++k) {
            int iv = (k == 0) ? iq.x : (k == 1) ? iq.y : (k == 2) ? iq.z : iq.w;
            if ((iv >> FB_BSZ_LOG2) == b) {
                int ee = e + k;
                int j  = nb[N_EDGE + ee];
                float qq  = q[ee];
                float fac = areas[j] / dens[j];
                float omq  = fmaxf(1.0f - qq, 0.0f);
                float dWdq = Cw * (-20.0f * qq * omq * omq * omq) * (1.0f / SUPPORT);
                float s = SUPPORT * fac * dWdq;
                float2 d = dist[ee];
                int loc = (iv & (FB_BSZ - 1)) << 1;
                atomicAdd(&lds[loc],     s * d.x);
                atomicAdd(&lds[loc + 1], s * d.y);
            }
        }
    }
    __syncthreads();
    float2* __restrict__ dst = (float2*)partials + (size_t)c * FB_NP_PAD + (size_t)b * FB_BSZ;
    const float2* __restrict__ src = (const float2*)lds;
    for (int k = threadIdx.x; k < FB_BSZ; k += blockDim.x) dst[k] = src[k];
}

__global__ __launch_bounds__(1024) void fb_pass2_binned(
    const int* __restrict__ nb, const float* __restrict__ areas,
    const float* __restrict__ rest, const float* __restrict__ q,
    const float2* __restrict__ dist, const float2* __restrict__ normals,
    float* __restrict__ partials, int C)
{
    __shared__ float lds[2 * FB_BSZ];
    const int b = blockIdx.x % FB_NBINS;
    const int c = blockIdx.x / FB_NBINS;
    for (int k = threadIdx.x; k < 2 * FB_BSZ; k += blockDim.x) lds[k] = 0.0f;
    __syncthreads();
    const int start = (int)((long long)c       * (N_EDGE / 4) / C) * 4;
    const int end   = (int)((long long)(c + 1) * (N_EDGE / 4) / C) * 4;
    const int4* __restrict__ nb4 = (const int4*)nb;
    for (int e = start + (int)threadIdx.x * 4; e < end; e += (int)blockDim.x * 4) {
        int4 iq = nb4[e >> 2];
        #pragma unroll
        for (int k = 0; k < 4; ++k) {
            int iv = (k == 0) ? iq.x : (k == 1) ? iq.y : (k == 2) ? iq.z : iq.w;
            if ((iv >> FB_BSZ_LOG2) == b) {
                int ee = e + k;
                int j  = nb[N_EDGE + ee];
                float2 ni = normals[iv];
                float2 nj = normals[j];
                float qq  = q[ee];
                float fc  = areas[j] * rest[j];
                float qm1 = qq - 1.0f;
                float t   = qm1 * qm1 * qm1 * qq * qq * qq;
                float kern = (qq <= 0.5f) ? fmaf(128.0f, t, 1.0f) : 64.0f * t;
                float2 d = dist[ee];
                int loc = (iv & (FB_BSZ - 1)) << 1;
                atomicAdd(&lds[loc],     -(ni.x - nj.x) + fc * kern * d.x);
                atomicAdd(&lds[loc + 1], -(ni.y - nj.y) + fc * kern * d.y);
            }
        }
    }
    __syncthreads();
    float2* __restrict__ dst = (float2*)partials + (size_t)c * FB_NP_PAD + (size_t)b * FB_BSZ;
    const float2* __restrict__ src = (const float2*)lds;
    for (int k = threadIdx.x; k < FB_BSZ; k += blockDim.x) dst[k] = src[k];
}

__global__ __launch_bounds__(256) void fb_reduce_partials(
    const float* __restrict__ partials, float* __restrict__ dst, int C)
{
    int p = blockIdx.x * blockDim.x + threadIdx.x;
    if (p >= N_PART) return;
    const float2* __restrict__ p2 = (const float2*)partials;
    float ax = 0.0f, ay = 0.0f;
    for (int c = 0; c < C; ++c) {
        float2 v = p2[(size_t)c * FB_NP_PAD + p];
        ax += v.x; ay += v.y;
    }
    ((float2*)dst)[p] = make_float2(ax, ay);
}

__global__ __launch_bounds__(256) void fb_zero2(float* __restrict__ a,
                                                float* __restrict__ b, int n) {
    int idx = blockIdx.x * blockDim.x + threadIdx.x;
    if (idx < n) { a[idx] = 0.0f; b[idx] = 0.0f; }
}

__global__ __launch_bounds__(256) void fb_pass1_atomic(
    const int* __restrict__ nb, const float* __restrict__ areas,
    const float* __restrict__ dens, const float* __restrict__ q,
    const float2* __restrict__ dist, float* __restrict__ normals)
{
    int e = blockIdx.x * blockDim.x + threadIdx.x;
    if (e >= N_EDGE) return;
    int i = nb[e];
    int j = nb[N_EDGE + e];
    float qq  = q[e];
    float fac = areas[j] / dens[j];
    const float Cw = 7.0f / (PI_F * SUPPORT * SUPPORT);
    float omq  = fmaxf(1.0f - qq, 0.0f);
    float dWdq = Cw * (-20.0f * qq * omq * omq * omq) * (1.0f / SUPPORT);
    float s = SUPPORT * fac * dWdq;
    float2 d = dist[e];
    atomicAdd(&normals[2 * i],     s * d.x);
    atomicAdd(&normals[2 * i + 1], s * d.y);
}

__global__ __launch_bounds__(256) void fb_pass2_atomic(
    const int* __restrict__ nb, const float* __restrict__ areas,
    const float* __restrict__ rest, const float* __restrict__ q,
    const float2* __restrict__ dist, const float2* __restrict__ normals,
    float* __restrict__ out)
{
    int e = blockIdx.x * blockDim.x + threadIdx.x;
    if (e >= N_EDGE) return;
    int i = nb[e];
    int j = nb[N_EDGE + e];
    float2 ni = normals[i];
    float2 nj = normals[j];
    float qq  = q[e];
    float fc  = areas[j] * rest[j];
    float qm1 = qq - 1.0f;
    float t   = qm1 * qm1 * qm1 * qq * qq * qq;
    float kern = (qq <= 0.5f) ? fmaf(128.0f, t, 1.0f) : 64.0f * t;
    float2 d = dist[e];
    atomicAdd(&out[2 * i],     -(ni.x - nj.x) + fc * kern * d.x);
    atomicAdd(&out[2 * i + 1], -(ni.y - nj.y) + fc * kern * d.y);
}

// ===========================================================================
extern "C" void kernel_launch(void* const* d_in, const int* in_sizes, int n_in,
                              void* d_out, int out_size, void* d_ws, size_t ws_size,
                              hipStream_t stream) {
    const int*   nb    = (const int*)d_in[0];     // [2*E]
    const float* areas = (const float*)d_in[1];   // [N]
    const float* dens  = (const float*)d_in[2];   // [N]
    const float* rest  = (const float*)d_in[3];   // [N]
    const float* q     = (const float*)d_in[4];   // [E]
    const float* dist  = (const float*)d_in[5];   // [E,2]
    float* out = (float*)d_out;                   // [N,2]

    // --- Sorted-path workspace layout ---
    size_t off = 0;
    auto take = [&](size_t bytes) { size_t o = off; off += (bytes + 255) & ~(size_t)255; return o; };
    size_t o_pack    = take((size_t)N_EDGE * sizeof(unsigned));
    size_t o_pay1    = take((size_t)N_EDGE * sizeof(float2));
    size_t o_pay2    = take((size_t)N_EDGE * sizeof(float2));
    size_t o_btab    = take((size_t)NCH * BT_STRIDE * sizeof(unsigned));
    size_t o_normals = take((size_t)N_PART * sizeof(float2));
    size_t o_fac     = take((size_t)N_PART * sizeof(float2));
    size_t base_need = off;
    const size_t per_g = (size_t)(NBIN * BINSZ) * sizeof(float2);

    int G = 0;
    if (ws_size > base_need) {
        G = (int)((ws_size - base_need) / per_g);
        if (G > G_MAX) G = G_MAX;
    }

    char* ws = (char*)d_ws;

    if (G >= 6) {
        unsigned* gpack   = (unsigned*)(ws + o_pack);
        float2*   gpay1   = (float2*)(ws + o_pay1);
        float2*   gpay2   = (float2*)(ws + o_pay2);
        unsigned* btab    = (unsigned*)(ws + o_btab);
        float2*   normals = (float2*)(ws + o_normals);
        float2*   fac     = (float2*)(ws + o_fac);
        float2*   partials= (float2*)(ws + base_need);

        prep_fac<<<(N_PART + 511) / 512, 512, 0, stream>>>(areas, dens, rest, fac);
        l1_sort<<<NCH, 512, 0, stream>>>(
            nb, fac, q, (const float2*)dist,
            gpack, gpay1, gpay2, btab);
        passB<<<NBIN * G, 512, 0, stream>>>(btab, gpack, gpay1, partials, G);
        reduceG<<<(N_PART + 255) / 256, 256, 0, stream>>>(partials, normals, G);
        passD<<<NBIN * G, 512, 0, stream>>>(btab, gpack, gpay2, normals, partials, G);
        reduceG<<<(N_PART + 255) / 256, 256, 0, stream>>>(partials, (float2*)out, G);
        return;
    }

    // --- Fallback paths ---
    const size_t normals_pad = 1 << 20;
    float* normals  = (float*)d_ws;
    float* partials = (float*)((char*)d_ws + normals_pad);
    const size_t per_chunk = (size_t)FB_NP_PAD * 2 * sizeof(float);
    int C = 0;
    if (ws_size > normals_pad) {
        C = (int)((ws_size - normals_pad) / per_chunk);
        if (C > FB_C_TARGET) C = FB_C_TARGET;
    }

    if (C >= 4) {
        const int grid = FB_NBINS * C;
        fb_pass1_binned<<<grid, 1024, 0, stream>>>(
            nb, areas, dens, q, (const float2*)dist, partials, C);
        fb_reduce_partials<<<(N_PART + 255) / 256, 256, 0, stream>>>(partials, normals, C);
        fb_pass2_binned<<<grid, 1024, 0, stream>>>(
            nb, areas, rest, q, (const float2*)dist, (const float2*)normals, partials, C);
        fb_reduce_partials<<<(N_PART + 255) / 256, 256, 0, stream>>>(partials, out, C);
    } else {
        const int nv = 2 * N_PART;
        fb_zero2<<<(nv + 255) / 256, 256, 0, stream>>>(normals, out, nv);
        const int blocks = (N_EDGE + 255) / 256;
        fb_pass1_atomic<<<blocks, 256, 0, stream>>>(
            nb, areas, dens, q, (const float2*)dist, normals);
        fb_pass2_atomic<<<blocks, 256, 0, stream>>>(
            nb, areas, rest, q, (const float2*)dist, (const float2*)normals, out);
    }
}